// Round 1
// baseline (78.258 us; speedup 1.0000x reference)
//
#include <hip/hip_runtime.h>
#include <hip/hip_bf16.h>

#define T_ 2048
#define E_ 768
#define H_ 64

typedef __attribute__((ext_vector_type(8))) __bf16 bf16x8;
typedef __attribute__((ext_vector_type(8))) unsigned short ushort8;
typedef __attribute__((ext_vector_type(4))) float floatx4;

static __device__ __forceinline__ unsigned short f2bf(float f) {
    union { float f; unsigned u; } v; v.f = f;
    unsigned u = v.u;
    u += 0x7FFFu + ((u >> 16) & 1u);   // round-to-nearest-even
    return (unsigned short)(u >> 16);
}

// ---------------- kernel 0: W [768][64] fp32 -> wT [3][64][768] bf16 ----------------
__global__ __launch_bounds__(256) void prep_wT(const float* __restrict__ Wq,
                                               const float* __restrict__ Wk,
                                               const float* __restrict__ Wv,
                                               unsigned short* __restrict__ wT) {
    int w  = blockIdx.x / 12;
    int k0 = (blockIdx.x % 12) * 64;
    const float* W = (w == 0) ? Wq : (w == 1 ? Wk : Wv);
    __shared__ unsigned short sm[64][65];
    int tid = threadIdx.x;
    #pragma unroll
    for (int i = 0; i < 16; ++i) {
        int idx = tid + i * 256;
        int k = idx >> 6, n = idx & 63;
        sm[n][k] = f2bf(W[(size_t)(k0 + k) * 64 + n]);
    }
    __syncthreads();
    #pragma unroll
    for (int i = 0; i < 16; ++i) {
        int idx = tid + i * 256;
        int n = idx >> 6, k = idx & 63;
        wT[(size_t)w * (64 * 768) + (size_t)n * 768 + k0 + k] = sm[n][k];
    }
}

// ---------------- kernel 1: QKV projection (bf16 MFMA GEMM) ----------------
// grid (128, 3), block 256. Block computes 64 rows x 64 cols of output widx.
__global__ __launch_bounds__(256) void qkv_proj(const float* __restrict__ x,
                                                const unsigned short* __restrict__ wT,
                                                unsigned short* __restrict__ Qb,
                                                unsigned short* __restrict__ Kb,
                                                unsigned short* __restrict__ Vb) {
    int widx = blockIdx.y;
    int t0   = blockIdx.x * 64;
    unsigned short* out = (widx == 0) ? Qb : (widx == 1 ? Kb : Vb);
    const unsigned short* wTw = wT + (size_t)widx * 64 * 768;

    __shared__ unsigned short xs[64][72];
    __shared__ unsigned short wts[64][72];

    int tid  = threadIdx.x;
    int lane = tid & 63, wv = tid >> 6;
    int r    = tid >> 2, seg = tid & 3;   // staging: row 0..63, 16-elem segment 0..3
    int lrow = lane & 15;
    int lk   = (lane >> 4) * 8;
    int qrow4 = (lane >> 4) * 4;

    floatx4 acc[4] = {};

    for (int k0 = 0; k0 < 768; k0 += 64) {
        // stage x (fp32 -> bf16): thread handles 16 contiguous floats
        {
            const float* xp = x + (size_t)(t0 + r) * 768 + k0 + seg * 16;
            float4 a0 = *(const float4*)(xp);
            float4 a1 = *(const float4*)(xp + 4);
            float4 a2 = *(const float4*)(xp + 8);
            float4 a3 = *(const float4*)(xp + 12);
            ushort8 b0, b1;
            b0[0] = f2bf(a0.x); b0[1] = f2bf(a0.y); b0[2] = f2bf(a0.z); b0[3] = f2bf(a0.w);
            b0[4] = f2bf(a1.x); b0[5] = f2bf(a1.y); b0[6] = f2bf(a1.z); b0[7] = f2bf(a1.w);
            b1[0] = f2bf(a2.x); b1[1] = f2bf(a2.y); b1[2] = f2bf(a2.z); b1[3] = f2bf(a2.w);
            b1[4] = f2bf(a3.x); b1[5] = f2bf(a3.y); b1[6] = f2bf(a3.z); b1[7] = f2bf(a3.w);
            *(ushort8*)&xs[r][seg * 16]     = b0;
            *(ushort8*)&xs[r][seg * 16 + 8] = b1;
        }
        // stage wT (already bf16): thread handles 16 contiguous elems
        {
            const ushort8* wp = (const ushort8*)(wTw + (size_t)r * 768 + k0 + seg * 16);
            *(ushort8*)&wts[r][seg * 16]     = wp[0];
            *(ushort8*)&wts[r][seg * 16 + 8] = wp[1];
        }
        __syncthreads();
        #pragma unroll
        for (int kc = 0; kc < 2; ++kc) {
            bf16x8 af = *(const bf16x8*)&xs[wv * 16 + lrow][kc * 32 + lk];
            #pragma unroll
            for (int nf = 0; nf < 4; ++nf) {
                bf16x8 bfv = *(const bf16x8*)&wts[nf * 16 + lrow][kc * 32 + lk];
                acc[nf] = __builtin_amdgcn_mfma_f32_16x16x32_bf16(af, bfv, acc[nf], 0, 0, 0);
            }
        }
        __syncthreads();
    }

    // fold 0.125 * log2(e) into Q so softmax runs in exp2 domain
    float qs = (widx == 0) ? 0.18033688011112042f : 1.0f;
    #pragma unroll
    for (int nf = 0; nf < 4; ++nf)
        #pragma unroll
        for (int rg = 0; rg < 4; ++rg) {
            size_t row = (size_t)(t0 + wv * 16 + qrow4 + rg);
            out[row * 64 + nf * 16 + lrow] = f2bf(acc[nf][rg] * qs);
        }
}

// ---------------- kernel 2: V [b][t][h] -> vT [b][h][t] ----------------
__global__ __launch_bounds__(256) void vtrans(const unsigned short* __restrict__ Vb,
                                              unsigned short* __restrict__ vT) {
    int b  = blockIdx.x >> 5;
    int t0 = (blockIdx.x & 31) * 64;
    __shared__ unsigned short sm[64][65];
    int tid = threadIdx.x;
    #pragma unroll
    for (int i = 0; i < 16; ++i) {
        int idx = tid + i * 256;
        int t = idx >> 6, h = idx & 63;
        sm[h][t] = Vb[(size_t)(b * T_ + t0 + t) * 64 + h];
    }
    __syncthreads();
    #pragma unroll
    for (int i = 0; i < 16; ++i) {
        int idx = tid + i * 256;
        int h = idx >> 6, t = idx & 63;
        vT[(size_t)(b * 64 + h) * T_ + t0 + t] = sm[h][t];
    }
}

// ---------------- kernel 3: flash attention, keys s >= t ----------------
// grid 128 (b*qtile), block 256 (4 waves x 16 q-rows). KV tiles of 64 from the diagonal up.
__global__ __launch_bounds__(256) void attn(const unsigned short* __restrict__ Qb,
                                            const unsigned short* __restrict__ Kb,
                                            const unsigned short* __restrict__ vT,
                                            float* __restrict__ out) {
    int b  = blockIdx.x & 3;
    int t0 = (blockIdx.x >> 2) * 64;

    __shared__ unsigned short ks[64][72];
    __shared__ unsigned short vts[64][72];
    __shared__ unsigned short ps[4][16][72];

    int tid  = threadIdx.x;
    int lane = tid & 63, wv = tid >> 6;
    int lrow = lane & 15;
    int lk   = (lane >> 4) * 8;
    int qrow4 = (lane >> 4) * 4;
    int sr = tid >> 2, sc = tid & 3;

    // Q fragments live in registers for the whole kernel (already scaled)
    bf16x8 qf[2];
    {
        const unsigned short* qp = Qb + (size_t)(b * T_ + t0 + wv * 16 + lrow) * 64 + lk;
        qf[0] = *(const bf16x8*)(qp);
        qf[1] = *(const bf16x8*)(qp + 32);
    }

    float m_[4], l_[4];
    floatx4 of[4] = {};
    #pragma unroll
    for (int rg = 0; rg < 4; ++rg) { m_[rg] = -__builtin_inff(); l_[rg] = 0.f; }

    for (int s0 = t0; s0 < T_; s0 += 64) {
        // stage K tile [s][h] and V^T tile [h][s]
        {
            const ushort8* kp = (const ushort8*)(Kb + (size_t)(b * T_ + s0 + sr) * 64 + sc * 16);
            ushort8 k0v = kp[0], k1v = kp[1];
            *(ushort8*)&ks[sr][sc * 16]     = k0v;
            *(ushort8*)&ks[sr][sc * 16 + 8] = k1v;
            const ushort8* vp = (const ushort8*)(vT + (size_t)(b * 64 + sr) * T_ + s0 + sc * 16);
            ushort8 v0v = vp[0], v1v = vp[1];
            *(ushort8*)&vts[sr][sc * 16]     = v0v;
            *(ushort8*)&vts[sr][sc * 16 + 8] = v1v;
        }
        __syncthreads();

        // S = Q K^T (exp2 domain; scale folded into Q)
        floatx4 sf[4] = {};
        #pragma unroll
        for (int kc = 0; kc < 2; ++kc) {
            bf16x8 af = qf[kc];
            #pragma unroll
            for (int nf = 0; nf < 4; ++nf) {
                bf16x8 bfv = *(const bf16x8*)&ks[nf * 16 + lrow][kc * 32 + lk];
                sf[nf] = __builtin_amdgcn_mfma_f32_16x16x32_bf16(af, bfv, sf[nf], 0, 0, 0);
            }
        }

        // mask on diagonal tile only: key s < query t  ->  -inf
        if (s0 == t0) {
            #pragma unroll
            for (int nf = 0; nf < 4; ++nf)
                #pragma unroll
                for (int rg = 0; rg < 4; ++rg) {
                    int sl = nf * 16 + lrow;
                    int ql = wv * 16 + qrow4 + rg;
                    if (sl < ql) sf[nf][rg] = -__builtin_inff();
                }
        }

        // online softmax: row max (in-lane over 4 frags, then 16-lane group reduce)
        float alpha[4];
        #pragma unroll
        for (int rg = 0; rg < 4; ++rg) {
            float v = fmaxf(fmaxf(sf[0][rg], sf[1][rg]), fmaxf(sf[2][rg], sf[3][rg]));
            v = fmaxf(v, __shfl_xor(v, 1, 64));
            v = fmaxf(v, __shfl_xor(v, 2, 64));
            v = fmaxf(v, __shfl_xor(v, 4, 64));
            v = fmaxf(v, __shfl_xor(v, 8, 64));
            float mn = fmaxf(m_[rg], v);
            alpha[rg] = exp2f(m_[rg] - mn);
            m_[rg] = mn;
            l_[rg] *= alpha[rg];
        }

        // P = exp2(S - m); lane-partial l; transpose P to MFMA-A layout via LDS
        #pragma unroll
        for (int nf = 0; nf < 4; ++nf)
            #pragma unroll
            for (int rg = 0; rg < 4; ++rg) {
                float p = exp2f(sf[nf][rg] - m_[rg]);
                l_[rg] += p;
                ps[wv][qrow4 + rg][nf * 16 + lrow] = f2bf(p);
            }

        // rescale O
        #pragma unroll
        for (int hf = 0; hf < 4; ++hf)
            #pragma unroll
            for (int rg = 0; rg < 4; ++rg)
                of[hf][rg] *= alpha[rg];

        // O += P V
        #pragma unroll
        for (int kc = 0; kc < 2; ++kc) {
            bf16x8 pa = *(const bf16x8*)&ps[wv][lrow][kc * 32 + lk];
            #pragma unroll
            for (int hf = 0; hf < 4; ++hf) {
                bf16x8 vbv = *(const bf16x8*)&vts[hf * 16 + lrow][kc * 32 + lk];
                of[hf] = __builtin_amdgcn_mfma_f32_16x16x32_bf16(pa, vbv, of[hf], 0, 0, 0);
            }
        }
        __syncthreads();
    }

    // deferred l reduction + normalize + store fp32
    #pragma unroll
    for (int rg = 0; rg < 4; ++rg) {
        float v = l_[rg];
        v += __shfl_xor(v, 1, 64);
        v += __shfl_xor(v, 2, 64);
        v += __shfl_xor(v, 4, 64);
        v += __shfl_xor(v, 8, 64);
        l_[rg] = 1.0f / v;
    }
    #pragma unroll
    for (int hf = 0; hf < 4; ++hf)
        #pragma unroll
        for (int rg = 0; rg < 4; ++rg) {
            size_t row = (size_t)(b * T_ + t0 + wv * 16 + qrow4 + rg);
            out[row * 64 + hf * 16 + lrow] = of[hf][rg] * l_[rg];
        }
}

extern "C" void kernel_launch(void* const* d_in, const int* in_sizes, int n_in,
                              void* d_out, int out_size, void* d_ws, size_t ws_size,
                              hipStream_t stream) {
    const float* x  = (const float*)d_in[0];
    const float* Wq = (const float*)d_in[1];
    const float* Wk = (const float*)d_in[2];
    const float* Wv = (const float*)d_in[3];
    float* out = (float*)d_out;

    unsigned short* wT = (unsigned short*)d_ws;       // 3*64*768
    unsigned short* Qb = wT + 3 * 64 * 768;           // 8192*64 each
    unsigned short* Kb = Qb + 8192 * 64;
    unsigned short* Vb = Kb + 8192 * 64;
    unsigned short* vT = Vb + 8192 * 64;              // [4][64][2048]

    prep_wT<<<36, 256, 0, stream>>>(Wq, Wk, Wv, wT);
    qkv_proj<<<dim3(128, 3), 256, 0, stream>>>(x, wT, Qb, Kb, Vb);
    vtrans<<<128, 256, 0, stream>>>(Vb, vT);
    attn<<<128, 256, 0, stream>>>(Qb, Kb, vT, out);
}

// Round 2
// 64.229 us; speedup vs baseline: 1.2184x; 1.2184x over previous
//
#include <hip/hip_runtime.h>
#include <hip/hip_bf16.h>

#define T_ 2048
#define E_ 768

typedef __attribute__((ext_vector_type(8))) __bf16 bf16x8;
typedef __attribute__((ext_vector_type(8))) unsigned short ushort8;
typedef __attribute__((ext_vector_type(4))) unsigned short ushort4v;
typedef __attribute__((ext_vector_type(4))) float floatx4;

static __device__ __forceinline__ unsigned short f2bf(float f) {
    union { float f; unsigned u; } v; v.f = f;
    unsigned u = v.u;
    u += 0x7FFFu + ((u >> 16) & 1u);   // round-to-nearest-even
    return (unsigned short)(u >> 16);
}

// ---------------- kernel 0: fused prep ----------------
// blocks 0..35:  W [768][64] fp32 -> wT [3][64][768] bf16
// blocks 36..:   x fp32 -> xb bf16 (flat copy)
__global__ __launch_bounds__(256) void prep(const float* __restrict__ x,
                                            const float* __restrict__ Wq,
                                            const float* __restrict__ Wk,
                                            const float* __restrict__ Wv,
                                            unsigned short* __restrict__ wT,
                                            unsigned short* __restrict__ xb) {
    int bid = blockIdx.x;
    int tid = threadIdx.x;
    if (bid < 36) {
        int w  = bid / 12;
        int k0 = (bid % 12) * 64;
        const float* W = (w == 0) ? Wq : (w == 1 ? Wk : Wv);
        __shared__ unsigned short sm[64][65];
        #pragma unroll
        for (int i = 0; i < 16; ++i) {
            int idx = tid + i * 256;
            int k = idx >> 6, n = idx & 63;
            sm[n][k] = f2bf(W[(size_t)(k0 + k) * 64 + n]);
        }
        __syncthreads();
        #pragma unroll
        for (int i = 0; i < 16; ++i) {
            int idx = tid + i * 256;
            int n = idx >> 6, k = idx & 63;
            wT[(size_t)w * (64 * 768) + (size_t)n * 768 + k0 + k] = sm[n][k];
        }
    } else {
        size_t base = (size_t)(bid - 36) * 4096 + (size_t)tid * 16;
        const float* xp = x + base;
        float4 a0 = *(const float4*)(xp);
        float4 a1 = *(const float4*)(xp + 4);
        float4 a2 = *(const float4*)(xp + 8);
        float4 a3 = *(const float4*)(xp + 12);
        ushort8 b0, b1;
        b0[0] = f2bf(a0.x); b0[1] = f2bf(a0.y); b0[2] = f2bf(a0.z); b0[3] = f2bf(a0.w);
        b0[4] = f2bf(a1.x); b0[5] = f2bf(a1.y); b0[6] = f2bf(a1.z); b0[7] = f2bf(a1.w);
        b1[0] = f2bf(a2.x); b1[1] = f2bf(a2.y); b1[2] = f2bf(a2.z); b1[3] = f2bf(a2.w);
        b1[4] = f2bf(a3.x); b1[5] = f2bf(a3.y); b1[6] = f2bf(a3.z); b1[7] = f2bf(a3.w);
        *(ushort8*)(xb + base)     = b0;
        *(ushort8*)(xb + base + 8) = b1;
    }
}

// ---------------- kernel 1: QKV projection ----------------
// grid (128, 3), block 256. x staged via LDS (bf16), W fragments direct from L2.
// widx==2 writes V transposed (vT[b][h][t]) -- no separate transpose pass.
__global__ __launch_bounds__(256) void qkv_proj(const unsigned short* __restrict__ xb,
                                                const unsigned short* __restrict__ wT,
                                                unsigned short* __restrict__ Qb,
                                                unsigned short* __restrict__ Kb,
                                                unsigned short* __restrict__ vT) {
    int widx = blockIdx.y;
    int t0   = blockIdx.x * 64;
    const unsigned short* wTw = wT + (size_t)widx * 64 * 768;

    __shared__ unsigned short xs[64][72];

    int tid  = threadIdx.x;
    int lane = tid & 63, wv = tid >> 6;
    int r    = tid >> 2, seg = tid & 3;
    int lrow = lane & 15;
    int lk   = (lane >> 4) * 8;
    int qrow4 = (lane >> 4) * 4;

    floatx4 acc[4] = {};

    for (int k0 = 0; k0 < 768; k0 += 64) {
        {
            const ushort8* xp = (const ushort8*)(xb + (size_t)(t0 + r) * 768 + k0 + seg * 16);
            ushort8 a0 = xp[0], a1 = xp[1];
            *(ushort8*)&xs[r][seg * 16]     = a0;
            *(ushort8*)&xs[r][seg * 16 + 8] = a1;
        }
        __syncthreads();
        #pragma unroll
        for (int kc = 0; kc < 2; ++kc) {
            bf16x8 af = *(const bf16x8*)&xs[wv * 16 + lrow][kc * 32 + lk];
            #pragma unroll
            for (int nf = 0; nf < 4; ++nf) {
                bf16x8 bfv = *(const bf16x8*)(wTw + (size_t)(nf * 16 + lrow) * 768 + k0 + kc * 32 + lk);
                acc[nf] = __builtin_amdgcn_mfma_f32_16x16x32_bf16(af, bfv, acc[nf], 0, 0, 0);
            }
        }
        __syncthreads();
    }

    if (widx == 2) {
        int b  = t0 >> 11;
        int tl = (t0 & 2047) + wv * 16 + qrow4;
        #pragma unroll
        for (int nf = 0; nf < 4; ++nf) {
            int h = nf * 16 + lrow;
            ushort4v pk;
            #pragma unroll
            for (int rg = 0; rg < 4; ++rg) pk[rg] = f2bf(acc[nf][rg]);
            *(ushort4v*)&vT[(size_t)(b * 64 + h) * T_ + tl] = pk;
        }
    } else {
        unsigned short* out = widx ? Kb : Qb;
        // fold 0.125 * log2(e) into Q so softmax runs in exp2 domain
        float qs = widx ? 1.0f : 0.18033688011112042f;
        #pragma unroll
        for (int nf = 0; nf < 4; ++nf)
            #pragma unroll
            for (int rg = 0; rg < 4; ++rg) {
                size_t row = (size_t)(t0 + wv * 16 + qrow4 + rg);
                out[row * 64 + nf * 16 + lrow] = f2bf(acc[nf][rg] * qs);
            }
    }
}

// ---------------- kernel 2: split-KV flash attention (partials) ----------------
// grid (8 chunks, 32 qtiles, 4 batch), block 256 (4 waves x 16 q-rows).
// chunk c covers keys s in [t0 + c*256, t0 + (c+1)*256) ∩ [t0, T).
__global__ __launch_bounds__(256) void attn_part(const unsigned short* __restrict__ Qb,
                                                 const unsigned short* __restrict__ Kb,
                                                 const unsigned short* __restrict__ vT,
                                                 float* __restrict__ mP,
                                                 float* __restrict__ lP,
                                                 float* __restrict__ oP) {
    int c  = blockIdx.x;
    int qt = blockIdx.y;
    int b  = blockIdx.z;
    int t0 = qt * 64;
    int sBeg = t0 + c * 256;
    if (sBeg >= T_) return;
    int sEnd = sBeg + 256; if (sEnd > T_) sEnd = T_;

    __shared__ unsigned short ks[64][72];
    __shared__ unsigned short vts[64][72];
    __shared__ unsigned short ps[4][16][72];

    int tid  = threadIdx.x;
    int lane = tid & 63, wv = tid >> 6;
    int lrow = lane & 15;
    int lk   = (lane >> 4) * 8;
    int qrow4 = (lane >> 4) * 4;
    int sr = tid >> 2, sc = tid & 3;

    bf16x8 qf[2];
    {
        const unsigned short* qp = Qb + (size_t)(b * T_ + t0 + wv * 16 + lrow) * 64 + lk;
        qf[0] = *(const bf16x8*)(qp);
        qf[1] = *(const bf16x8*)(qp + 32);
    }

    float m_[4], l_[4];
    floatx4 of[4] = {};
    #pragma unroll
    for (int rg = 0; rg < 4; ++rg) { m_[rg] = -__builtin_inff(); l_[rg] = 0.f; }

    for (int s0 = sBeg; s0 < sEnd; s0 += 64) {
        {
            const ushort8* kp = (const ushort8*)(Kb + (size_t)(b * T_ + s0 + sr) * 64 + sc * 16);
            ushort8 k0v = kp[0], k1v = kp[1];
            *(ushort8*)&ks[sr][sc * 16]     = k0v;
            *(ushort8*)&ks[sr][sc * 16 + 8] = k1v;
            const ushort8* vp = (const ushort8*)(vT + (size_t)(b * 64 + sr) * T_ + s0 + sc * 16);
            ushort8 v0v = vp[0], v1v = vp[1];
            *(ushort8*)&vts[sr][sc * 16]     = v0v;
            *(ushort8*)&vts[sr][sc * 16 + 8] = v1v;
        }
        __syncthreads();

        floatx4 sf[4] = {};
        #pragma unroll
        for (int kc = 0; kc < 2; ++kc) {
            bf16x8 af = qf[kc];
            #pragma unroll
            for (int nf = 0; nf < 4; ++nf) {
                bf16x8 bfv = *(const bf16x8*)&ks[nf * 16 + lrow][kc * 32 + lk];
                sf[nf] = __builtin_amdgcn_mfma_f32_16x16x32_bf16(af, bfv, sf[nf], 0, 0, 0);
            }
        }

        if (s0 == t0) {   // diagonal tile: key s < query t -> -inf
            #pragma unroll
            for (int nf = 0; nf < 4; ++nf)
                #pragma unroll
                for (int rg = 0; rg < 4; ++rg) {
                    int sl = nf * 16 + lrow;
                    int ql = wv * 16 + qrow4 + rg;
                    if (sl < ql) sf[nf][rg] = -__builtin_inff();
                }
        }

        float alpha[4];
        #pragma unroll
        for (int rg = 0; rg < 4; ++rg) {
            float v = fmaxf(fmaxf(sf[0][rg], sf[1][rg]), fmaxf(sf[2][rg], sf[3][rg]));
            v = fmaxf(v, __shfl_xor(v, 1, 64));
            v = fmaxf(v, __shfl_xor(v, 2, 64));
            v = fmaxf(v, __shfl_xor(v, 4, 64));
            v = fmaxf(v, __shfl_xor(v, 8, 64));
            float mn = fmaxf(m_[rg], v);
            alpha[rg] = exp2f(m_[rg] - mn);
            m_[rg] = mn;
            l_[rg] *= alpha[rg];
        }

        #pragma unroll
        for (int nf = 0; nf < 4; ++nf)
            #pragma unroll
            for (int rg = 0; rg < 4; ++rg) {
                float p = exp2f(sf[nf][rg] - m_[rg]);
                l_[rg] += p;
                ps[wv][qrow4 + rg][nf * 16 + lrow] = f2bf(p);
            }

        #pragma unroll
        for (int hf = 0; hf < 4; ++hf)
            #pragma unroll
            for (int rg = 0; rg < 4; ++rg)
                of[hf][rg] *= alpha[rg];

        #pragma unroll
        for (int kc = 0; kc < 2; ++kc) {
            bf16x8 pa = *(const bf16x8*)&ps[wv][lrow][kc * 32 + lk];
            #pragma unroll
            for (int hf = 0; hf < 4; ++hf) {
                bf16x8 vbv = *(const bf16x8*)&vts[hf * 16 + lrow][kc * 32 + lk];
                of[hf] = __builtin_amdgcn_mfma_f32_16x16x32_bf16(pa, vbv, of[hf], 0, 0, 0);
            }
        }
        __syncthreads();
    }

    // epilogue: store unnormalized partials
    int p = (b * 32 + qt) * 8 + c;
    #pragma unroll
    for (int rg = 0; rg < 4; ++rg) {
        float v = l_[rg];
        v += __shfl_xor(v, 1, 64);
        v += __shfl_xor(v, 2, 64);
        v += __shfl_xor(v, 4, 64);
        v += __shfl_xor(v, 8, 64);
        l_[rg] = v;
    }
    if (lrow == 0) {
        #pragma unroll
        for (int rg = 0; rg < 4; ++rg) {
            int row = wv * 16 + qrow4 + rg;
            mP[(size_t)p * 64 + row] = m_[rg];
            lP[(size_t)p * 64 + row] = l_[rg];
        }
    }
    #pragma unroll
    for (int hf = 0; hf < 4; ++hf)
        #pragma unroll
        for (int rg = 0; rg < 4; ++rg) {
            int row = wv * 16 + qrow4 + rg;
            oP[((size_t)p * 64 + row) * 64 + hf * 16 + lrow] = of[hf][rg];
        }
}

// ---------------- kernel 3: combine partials ----------------
// grid 512: block = (b,qtile, quarter of rows). 256 threads: 16 rows x 64 cols, float4 per thread.
__global__ __launch_bounds__(256) void combine(const float* __restrict__ mP,
                                               const float* __restrict__ lP,
                                               const float* __restrict__ oP,
                                               float* __restrict__ out) {
    int bq = blockIdx.x >> 2;       // 0..127 = b*32+qt
    int rq = blockIdx.x & 3;
    int qt = bq & 31;
    int b  = bq >> 5;
    int nch = (32 - qt + 3) >> 2;

    int tid = threadIdx.x;
    int r   = rq * 16 + (tid >> 4);
    int cb  = (tid & 15) * 4;

    float M = -__builtin_inff();
    for (int cc = 0; cc < nch; ++cc)
        M = fmaxf(M, mP[(size_t)(bq * 8 + cc) * 64 + r]);

    float L = 0.f;
    float4 o = {0.f, 0.f, 0.f, 0.f};
    for (int cc = 0; cc < nch; ++cc) {
        size_t p = (size_t)(bq * 8 + cc);
        float w = exp2f(mP[p * 64 + r] - M);
        L += lP[p * 64 + r] * w;
        float4 ov = *(const float4*)&oP[(p * 64 + r) * 64 + cb];
        o.x += ov.x * w; o.y += ov.y * w; o.z += ov.z * w; o.w += ov.w * w;
    }
    float inv = 1.0f / L;
    float4 res = {o.x * inv, o.y * inv, o.z * inv, o.w * inv};
    *(float4*)&out[((size_t)(b * T_ + qt * 64 + r)) * 64 + cb] = res;
}

extern "C" void kernel_launch(void* const* d_in, const int* in_sizes, int n_in,
                              void* d_out, int out_size, void* d_ws, size_t ws_size,
                              hipStream_t stream) {
    const float* x  = (const float*)d_in[0];
    const float* Wq = (const float*)d_in[1];
    const float* Wk = (const float*)d_in[2];
    const float* Wv = (const float*)d_in[3];
    float* out = (float*)d_out;

    // workspace layout (bytes): wT 288K | Qb 1M | Kb 1M | vT 1M | mP 256K | lP 256K | oP 16.75M
    // xb (12.6M bf16) overlays oP -- dead after qkv_proj, before attn_part writes oP.
    unsigned short* wT = (unsigned short*)d_ws;
    unsigned short* Qb = wT + 3 * 64 * 768;
    unsigned short* Kb = Qb + 8192 * 64;
    unsigned short* vT = Kb + 8192 * 64;
    float* mP = (float*)(vT + 4 * 64 * T_);
    float* lP = mP + 1024 * 64;
    float* oP = lP + 1024 * 64;
    unsigned short* xb = (unsigned short*)oP;

    prep<<<36 + 1536, 256, 0, stream>>>(x, Wq, Wk, Wv, wT, xb);
    qkv_proj<<<dim3(128, 3), 256, 0, stream>>>(xb, wT, Qb, Kb, vT);
    attn_part<<<dim3(8, 32, 4), 256, 0, stream>>>(Qb, Kb, vT, mP, lP, oP);
    combine<<<512, 256, 0, stream>>>(mP, lP, oP, out);
}